// Round 1
// baseline (615.421 us; speedup 1.0000x reference)
//
#include <hip/hip_runtime.h>

// ---------------------------------------------------------------------------
// Attention (LSA, ViT-style) for MI355X / gfx950.
// B=32, N=577, DIM=768, H=12, DH=64. All f16 MFMA (16x16x32), fp32 accumulate.
// Pipeline: transpose weights -> QKV GEMM (scatter q,k,[v^T]) -> flash attn
//           -> out-proj GEMM (+bias, fp32 out).
// ---------------------------------------------------------------------------

typedef _Float16 half8  __attribute__((ext_vector_type(8)));
typedef _Float16 half4v __attribute__((ext_vector_type(4)));
typedef float    floatx4 __attribute__((ext_vector_type(4)));

#define MTOT   18464          // B*N = 32*577
#define NEG_V  (-987654321.0f)
#define VTS    584            // padded row stride for V^T (multiple of 8)

// ---------------- weight transpose: src[K][Ncol] f32 -> dst[Ncol][K] f16 ----
__global__ __launch_bounds__(256) void transpose_w(const float* __restrict__ src,
                                                   _Float16* __restrict__ dst,
                                                   int K, int Ncol) {
    __shared__ float tile[32][33];
    const int n0 = blockIdx.x * 32, k0 = blockIdx.y * 32;
    const int tx = threadIdx.x & 31, ty = threadIdx.x >> 5;   // 32 x 8
    for (int i = 0; i < 32; i += 8)
        tile[ty + i][tx] = src[(size_t)(k0 + ty + i) * Ncol + (n0 + tx)];
    __syncthreads();
    for (int i = 0; i < 32; i += 8)
        dst[(size_t)(n0 + ty + i) * K + (k0 + tx)] = (_Float16)tile[tx][ty + i];
}

// ---------------- GEMM1: qkv = x @ W_qkv, scatter to q,k,v^T (f16) ----------
// x [18464][768] f32, wT [2304][768] f16. Tile 128x128, BK=32, 4 waves.
__global__ __launch_bounds__(256) void gemm_qkv(const float* __restrict__ x,
                                                const _Float16* __restrict__ wT,
                                                _Float16* __restrict__ qg,
                                                _Float16* __restrict__ kg,
                                                _Float16* __restrict__ vT) {
    __shared__ _Float16 As[128][40];   // row stride 80B -> 2-way-only conflicts
    __shared__ _Float16 Bs[128][40];
    const int m0 = blockIdx.x * 128, n0 = blockIdx.y * 128;
    const int tid = threadIdx.x;
    const int lane = tid & 63, wv = tid >> 6;
    const int wrow = wv >> 1, wcol = wv & 1;
    const int lr = lane & 15, lq = lane >> 4;

    floatx4 acc[4][4];
    const floatx4 fz = {0.f, 0.f, 0.f, 0.f};
    for (int i = 0; i < 4; ++i)
        for (int j = 0; j < 4; ++j) acc[i][j] = fz;

    for (int kk = 0; kk < 768; kk += 32) {
        __syncthreads();
        // stage A: 128 rows x 32 f32 -> f16 (4 chunks/thread)
        #pragma unroll
        for (int c = tid; c < 1024; c += 256) {
            const int r = c >> 3, ch = c & 7;
            const int gr = m0 + r;
            float4 v = {0.f, 0.f, 0.f, 0.f};
            if (gr < MTOT) v = *(const float4*)(x + (size_t)gr * 768 + kk + ch * 4);
            half4v hv = {(_Float16)v.x, (_Float16)v.y, (_Float16)v.z, (_Float16)v.w};
            *(half4v*)&As[r][ch * 4] = hv;
        }
        // stage B: 128 rows x 32 f16 (2 chunks/thread)
        #pragma unroll
        for (int c = tid; c < 512; c += 256) {
            const int r = c >> 2, ch = c & 3;
            half8 v = *(const half8*)(wT + (size_t)(n0 + r) * 768 + kk + ch * 8);
            *(half8*)&Bs[r][ch * 8] = v;
        }
        __syncthreads();
        half8 af[4], bf[4];
        #pragma unroll
        for (int i = 0; i < 4; ++i) af[i] = *(const half8*)&As[wrow * 64 + i * 16 + lr][lq * 8];
        #pragma unroll
        for (int j = 0; j < 4; ++j) bf[j] = *(const half8*)&Bs[wcol * 64 + j * 16 + lr][lq * 8];
        #pragma unroll
        for (int i = 0; i < 4; ++i)
            #pragma unroll
            for (int j = 0; j < 4; ++j)
                acc[i][j] = __builtin_amdgcn_mfma_f32_16x16x32_f16(af[i], bf[j], acc[i][j], 0, 0, 0);
    }

    // epilogue: scatter into q [b,h,n,d], k [b,h,n,d], v^T [b,h,d,VTS]
    #pragma unroll
    for (int j = 0; j < 4; ++j) {
        const int c = n0 + wcol * 64 + j * 16 + lr;      // output feature 0..2303
        const int which = c / 768;                        // 0=q 1=k 2=v (tile-uniform)
        const int rem = c - which * 768;
        const int h = rem >> 6, d = rem & 63;
        #pragma unroll
        for (int i = 0; i < 4; ++i)
            #pragma unroll
            for (int r = 0; r < 4; ++r) {
                const int row = m0 + wrow * 64 + i * 16 + lq * 4 + r;
                if (row >= MTOT) continue;
                const unsigned bb = (unsigned)row / 577u;
                const unsigned nn = (unsigned)row - bb * 577u;
                const _Float16 val = (_Float16)acc[i][j][r];
                const size_t head = (size_t)(bb * 12 + h);
                if (which == 0)      qg[(head * 577 + nn) * 64 + d] = val;
                else if (which == 1) kg[(head * 577 + nn) * 64 + d] = val;
                else                 vT[(head * 64 + d) * VTS + nn] = val;
            }
    }
}

// ---------------- flash attention: per (b,h,qtile64) block, 4 waves ---------
__global__ __launch_bounds__(256) void attn_kernel(const _Float16* __restrict__ qg,
                                                   const _Float16* __restrict__ kg,
                                                   const _Float16* __restrict__ vT,
                                                   const float* __restrict__ scale,
                                                   _Float16* __restrict__ Og) {
    __shared__ _Float16 Ks[64][72];   // K tile  [j][d], 144B stride
    __shared__ _Float16 Vs[64][72];   // V^T tile [d][j]
    __shared__ _Float16 Ps[64][72];   // P round-trip [i][j]
    const int qt = blockIdx.x, h = blockIdx.y, b = blockIdx.z;
    const int tid = threadIdx.x, lane = tid & 63, wv = tid >> 6;
    const int lr = lane & 15, lq = lane >> 4;
    const size_t head = (size_t)(b * 12 + h);
    const _Float16* qh = qg + head * 577 * 64;
    const _Float16* kh = kg + head * 577 * 64;
    const _Float16* vh = vT + head * 64 * VTS;
    const float sc = scale[h];
    const int q0 = qt * 64;

    // Q fragments (A-operand): lane holds Q[q0+wv*16+lr][lq*8 + frag*32 ..+8]
    const int qi = q0 + wv * 16 + lr;
    const int qc = qi < 577 ? qi : 576;          // clamp; invalid rows never stored
    const half8 aq0 = *(const half8*)(qh + (size_t)qc * 64 + lq * 8);
    const half8 aq1 = *(const half8*)(qh + (size_t)qc * 64 + 32 + lq * 8);

    const floatx4 fz = {0.f, 0.f, 0.f, 0.f};
    floatx4 o[4];
    for (int ct = 0; ct < 4; ++ct) o[ct] = fz;
    float m_i[4], l_i[4];
    for (int r = 0; r < 4; ++r) { m_i[r] = -INFINITY; l_i[r] = 0.f; }

    for (int kt = 0; kt < 10; ++kt) {
        const int j0 = kt * 64;
        __syncthreads();
        // stage K tile [j][d]
        #pragma unroll
        for (int c = tid; c < 512; c += 256) {
            const int r = c >> 3, ch = c & 7;
            const int j = j0 + r;
            half8 v = {};
            if (j < 577) v = *(const half8*)(kh + (size_t)j * 64 + ch * 8);
            *(half8*)&Ks[r][ch * 8] = v;
        }
        // stage V^T tile [d][j]
        #pragma unroll
        for (int c = tid; c < 512; c += 256) {
            const int d = c >> 3, ch = c & 7;
            const int nbase = j0 + ch * 8;
            half8 v = {};
            if (nbase < 577) {
                v = *(const half8*)(vh + (size_t)d * VTS + nbase);
                if (nbase + 8 > 577) {
                    #pragma unroll
                    for (int t = 0; t < 8; ++t)
                        if (nbase + t >= 577) v[t] = (_Float16)0;
                }
            }
            *(half8*)&Vs[d][ch * 8] = v;
        }
        __syncthreads();

        // S = Q K^T  (wave's 16 rows x 64 cols)
        floatx4 s[4];
        #pragma unroll
        for (int ct = 0; ct < 4; ++ct) {
            const half8 b0 = *(const half8*)&Ks[ct * 16 + lr][lq * 8];
            const half8 b1 = *(const half8*)&Ks[ct * 16 + lr][32 + lq * 8];
            floatx4 t = fz;
            t = __builtin_amdgcn_mfma_f32_16x16x32_f16(aq0, b0, t, 0, 0, 0);
            t = __builtin_amdgcn_mfma_f32_16x16x32_f16(aq1, b1, t, 0, 0, 0);
            s[ct] = t;
        }

        // scale, diagonal NEG mask, pad mask; row-max
        float mt[4];
        #pragma unroll
        for (int r = 0; r < 4; ++r) {
            const int i = q0 + wv * 16 + lq * 4 + r;
            #pragma unroll
            for (int ct = 0; ct < 4; ++ct) {
                const int j = j0 + ct * 16 + lr;
                float val = s[ct][r] * sc;
                if (i == j) val = NEG_V;
                if (j >= 577) val = -INFINITY;
                s[ct][r] = val;
            }
            mt[r] = fmaxf(fmaxf(s[0][r], s[1][r]), fmaxf(s[2][r], s[3][r]));
        }
        #pragma unroll
        for (int off = 1; off < 16; off <<= 1)
            #pragma unroll
            for (int r = 0; r < 4; ++r) mt[r] = fmaxf(mt[r], __shfl_xor(mt[r], off, 64));

        float alpha[4], rs[4];
        #pragma unroll
        for (int r = 0; r < 4; ++r) {
            const float mn = fmaxf(m_i[r], mt[r]);
            alpha[r] = __expf(m_i[r] - mn);   // exp(-inf)=0 on first tile
            m_i[r] = mn;
            rs[r] = 0.f;
        }
        #pragma unroll
        for (int ct = 0; ct < 4; ++ct)
            #pragma unroll
            for (int r = 0; r < 4; ++r) {
                const float p = __expf(s[ct][r] - m_i[r]);
                s[ct][r] = p;
                rs[r] += p;
            }
        #pragma unroll
        for (int off = 1; off < 16; off <<= 1)
            #pragma unroll
            for (int r = 0; r < 4; ++r) rs[r] += __shfl_xor(rs[r], off, 64);
        #pragma unroll
        for (int r = 0; r < 4; ++r) l_i[r] = l_i[r] * alpha[r] + rs[r];

        // P -> LDS (C/D layout -> A-operand layout), rescale O
        #pragma unroll
        for (int ct = 0; ct < 4; ++ct)
            #pragma unroll
            for (int r = 0; r < 4; ++r) {
                Ps[wv * 16 + lq * 4 + r][ct * 16 + lr] = (_Float16)s[ct][r];
                o[ct][r] *= alpha[r];
            }

        // O += P V  (wave reads only its own 16 Ps rows -> no barrier needed)
        const half8 ap0 = *(const half8*)&Ps[wv * 16 + lr][lq * 8];
        const half8 ap1 = *(const half8*)&Ps[wv * 16 + lr][32 + lq * 8];
        #pragma unroll
        for (int ct = 0; ct < 4; ++ct) {
            const half8 b0 = *(const half8*)&Vs[ct * 16 + lr][lq * 8];
            const half8 b1 = *(const half8*)&Vs[ct * 16 + lr][32 + lq * 8];
            o[ct] = __builtin_amdgcn_mfma_f32_16x16x32_f16(ap0, b0, o[ct], 0, 0, 0);
            o[ct] = __builtin_amdgcn_mfma_f32_16x16x32_f16(ap1, b1, o[ct], 0, 0, 0);
        }
    }

    // write O [b*577+i][h*64 + d] as f16
    #pragma unroll
    for (int ct = 0; ct < 4; ++ct)
        #pragma unroll
        for (int r = 0; r < 4; ++r) {
            const int i = q0 + wv * 16 + lq * 4 + r;
            if (i < 577) {
                const float val = o[ct][r] / l_i[r];
                Og[((size_t)(b * 577 + i)) * 768 + h * 64 + ct * 16 + lr] = (_Float16)val;
            }
        }
}

// ---------------- GEMM2: out = O @ W_out + b_out (fp32 out) -----------------
__global__ __launch_bounds__(256) void gemm_out(const _Float16* __restrict__ Og,
                                                const _Float16* __restrict__ wT,
                                                const float* __restrict__ bias,
                                                float* __restrict__ out) {
    __shared__ _Float16 As[128][40];
    __shared__ _Float16 Bs[128][40];
    const int m0 = blockIdx.x * 128, n0 = blockIdx.y * 128;
    const int tid = threadIdx.x;
    const int lane = tid & 63, wv = tid >> 6;
    const int wrow = wv >> 1, wcol = wv & 1;
    const int lr = lane & 15, lq = lane >> 4;

    floatx4 acc[4][4];
    const floatx4 fz = {0.f, 0.f, 0.f, 0.f};
    for (int i = 0; i < 4; ++i)
        for (int j = 0; j < 4; ++j) acc[i][j] = fz;

    for (int kk = 0; kk < 768; kk += 32) {
        __syncthreads();
        #pragma unroll
        for (int c = tid; c < 512; c += 256) {
            const int r = c >> 2, ch = c & 3;
            const int gr = m0 + r;
            half8 v = {};
            if (gr < MTOT) v = *(const half8*)(Og + (size_t)gr * 768 + kk + ch * 8);
            *(half8*)&As[r][ch * 8] = v;
        }
        #pragma unroll
        for (int c = tid; c < 512; c += 256) {
            const int r = c >> 2, ch = c & 3;
            half8 v = *(const half8*)(wT + (size_t)(n0 + r) * 768 + kk + ch * 8);
            *(half8*)&Bs[r][ch * 8] = v;
        }
        __syncthreads();
        half8 af[4], bf[4];
        #pragma unroll
        for (int i = 0; i < 4; ++i) af[i] = *(const half8*)&As[wrow * 64 + i * 16 + lr][lq * 8];
        #pragma unroll
        for (int j = 0; j < 4; ++j) bf[j] = *(const half8*)&Bs[wcol * 64 + j * 16 + lr][lq * 8];
        #pragma unroll
        for (int i = 0; i < 4; ++i)
            #pragma unroll
            for (int j = 0; j < 4; ++j)
                acc[i][j] = __builtin_amdgcn_mfma_f32_16x16x32_f16(af[i], bf[j], acc[i][j], 0, 0, 0);
    }

    #pragma unroll
    for (int j = 0; j < 4; ++j) {
        const int c = n0 + wcol * 64 + j * 16 + lr;
        const float bv = bias[c];
        #pragma unroll
        for (int i = 0; i < 4; ++i)
            #pragma unroll
            for (int r = 0; r < 4; ++r) {
                const int row = m0 + wrow * 64 + i * 16 + lq * 4 + r;
                if (row < MTOT) out[(size_t)row * 768 + c] = acc[i][j][r] + bv;
            }
    }
}

// ---------------------------------------------------------------------------
extern "C" void kernel_launch(void* const* d_in, const int* in_sizes, int n_in,
                              void* d_out, int out_size, void* d_ws, size_t ws_size,
                              hipStream_t stream) {
    const float* x      = (const float*)d_in[0];   // [32,577,768]
    const float* W_qkv  = (const float*)d_in[1];   // [768,2304]
    const float* scale  = (const float*)d_in[2];   // [12]
    const float* W_out  = (const float*)d_in[3];   // [768,768]
    const float* b_out  = (const float*)d_in[4];   // [768]
    float* out = (float*)d_out;

    // workspace layout (f16):
    //   q [32,12,577,64]  28,360,704 B
    //   k [32,12,577,64]  28,360,704 B
    //   vT[32,12,64,584]  28,704,768 B
    //   O [18464,768]     28,360,704 B
    //   WqkvT [2304,768]   3,538,944 B
    //   WoutT [768,768]    1,179,648 B     total ~113 MB
    char* ws = (char*)d_ws;
    _Float16* qg    = (_Float16*)(ws);
    _Float16* kg    = (_Float16*)(ws + 28360704u);
    _Float16* vT    = (_Float16*)(ws + 2u * 28360704u);
    _Float16* Og    = (_Float16*)(ws + 2u * 28360704u + 28704768u);
    _Float16* WqkvT = (_Float16*)(ws + 3u * 28360704u + 28704768u);
    _Float16* WoutT = WqkvT + (size_t)2304 * 768;

    transpose_w<<<dim3(72, 24), 256, 0, stream>>>(W_qkv, WqkvT, 768, 2304);
    transpose_w<<<dim3(24, 24), 256, 0, stream>>>(W_out, WoutT, 768, 768);
    gemm_qkv<<<dim3(145, 18), 256, 0, stream>>>(x, WqkvT, qg, kg, vT);
    attn_kernel<<<dim3(10, 12, 32), 256, 0, stream>>>(qg, kg, vT, scale, Og);
    gemm_out<<<dim3(145, 6), 256, 0, stream>>>(Og, WoutT, b_out, out);
}

// Round 2
// 474.573 us; speedup vs baseline: 1.2968x; 1.2968x over previous
//
#include <hip/hip_runtime.h>

// ---------------------------------------------------------------------------
// Attention (LSA, ViT-style) for MI355X / gfx950.
// B=32, N=577, DIM=768, H=12, DH=64. All f16 MFMA (16x16x32), fp32 accumulate.
// Pipeline: cvt x->f16 | transpose weights -> QKV GEMM (global_load_lds,
//           scatter q,k,v^T) -> flash attn -> out-proj GEMM (+bias, fp32 out).
// ---------------------------------------------------------------------------

typedef _Float16 half8  __attribute__((ext_vector_type(8)));
typedef float    floatx4 __attribute__((ext_vector_type(4)));

#define MTOT   18464          // B*N = 32*577
#define MPAD   18560          // 145*128 (GEMM row padding; zero-filled)
#define NEG_V  (-987654321.0f)
#define VTS    584            // padded row stride for V^T (multiple of 8)

// async 16B global->LDS (direct-to-shared DMA; LDS dst = uniform base + lane*16)
__device__ __forceinline__ void gl_lds16(const _Float16* g, _Float16* l) {
    __builtin_amdgcn_global_load_lds(
        (const __attribute__((address_space(1))) unsigned int*)g,
        (__attribute__((address_space(3))) unsigned int*)l,
        16, 0, 0);
}

// ---------------- x fp32 -> f16, padded+zero-filled to MPAD rows ------------
__global__ __launch_bounds__(256) void cvt_x(const float* __restrict__ x,
                                             _Float16* __restrict__ x16) {
    const size_t idx = ((size_t)blockIdx.x * 256 + threadIdx.x) * 8;
    half8 h = {};
    if (idx < (size_t)MTOT * 768) {
        float4 a = *(const float4*)(x + idx);
        float4 b = *(const float4*)(x + idx + 4);
        h[0] = (_Float16)a.x; h[1] = (_Float16)a.y;
        h[2] = (_Float16)a.z; h[3] = (_Float16)a.w;
        h[4] = (_Float16)b.x; h[5] = (_Float16)b.y;
        h[6] = (_Float16)b.z; h[7] = (_Float16)b.w;
    }
    *(half8*)(x16 + idx) = h;
}

// ---------------- weight transpose: src[K][Ncol] f32 -> dst[Ncol][K] f16 ----
__global__ __launch_bounds__(256) void transpose_w(const float* __restrict__ src,
                                                   _Float16* __restrict__ dst,
                                                   int K, int Ncol) {
    __shared__ float tile[32][33];
    const int n0 = blockIdx.x * 32, k0 = blockIdx.y * 32;
    const int tx = threadIdx.x & 31, ty = threadIdx.x >> 5;   // 32 x 8
    for (int i = 0; i < 32; i += 8)
        tile[ty + i][tx] = src[(size_t)(k0 + ty + i) * Ncol + (n0 + tx)];
    __syncthreads();
    for (int i = 0; i < 32; i += 8)
        dst[(size_t)(n0 + ty + i) * K + (k0 + tx)] = (_Float16)tile[tx][ty + i];
}

// ---------------- GEMM1: qkv = x16 @ W_qkv^T, scatter to q,k,v^T (f16) ------
// x16 [MPAD][768] f16, wT [2304][768] f16. Tile 128x128, BK=32, 4 waves.
// LDS tiles unpadded [128][32] f16 (64B rows) as global_load_lds requires;
// b128 fragment reads hit a uniform 8-touches-per-bank pattern (b128 optimum).
__global__ __launch_bounds__(256) void gemm_qkv(const _Float16* __restrict__ x16,
                                                const _Float16* __restrict__ wT,
                                                _Float16* __restrict__ qg,
                                                _Float16* __restrict__ kg,
                                                _Float16* __restrict__ vT) {
    __shared__ _Float16 As[128 * 32];
    __shared__ _Float16 Bs[128 * 32];
    const int m0 = blockIdx.x * 128, n0 = blockIdx.y * 128;
    const int tid = threadIdx.x;
    const int lane = tid & 63, wv = tid >> 6;
    const int wrow = wv >> 1, wcol = wv & 1;
    const int lr = lane & 15, lq = lane >> 4;

    floatx4 acc[4][4];
    const floatx4 fz = {0.f, 0.f, 0.f, 0.f};
    for (int i = 0; i < 4; ++i)
        for (int j = 0; j < 4; ++j) acc[i][j] = fz;

    for (int kk = 0; kk < 768; kk += 32) {
        __syncthreads();
        // stage A+B: 512 16B-chunks each; chunk c -> row c>>2, 8-f16 group c&3.
        // LDS base (elems) = (wv*64 + t*256)*8 (wave-uniform); HW adds lane*16B.
        #pragma unroll
        for (int t = 0; t < 2; ++t) {
            const int c = wv * 64 + t * 256 + lane;
            const int r = c >> 2, ch = c & 3;
            gl_lds16(x16 + (size_t)(m0 + r) * 768 + kk + ch * 8,
                     As + (wv * 64 + t * 256) * 8);
            gl_lds16(wT + (size_t)(n0 + r) * 768 + kk + ch * 8,
                     Bs + (wv * 64 + t * 256) * 8);
        }
        __syncthreads();
        half8 af[4], bf[4];
        #pragma unroll
        for (int i = 0; i < 4; ++i)
            af[i] = *(const half8*)&As[(wrow * 64 + i * 16 + lr) * 32 + lq * 8];
        #pragma unroll
        for (int j = 0; j < 4; ++j)
            bf[j] = *(const half8*)&Bs[(wcol * 64 + j * 16 + lr) * 32 + lq * 8];
        #pragma unroll
        for (int i = 0; i < 4; ++i)
            #pragma unroll
            for (int j = 0; j < 4; ++j)
                acc[i][j] = __builtin_amdgcn_mfma_f32_16x16x32_f16(af[i], bf[j], acc[i][j], 0, 0, 0);
    }

    // epilogue: scatter into q [b,h,n,d], k [b,h,n,d], v^T [b,h,d,VTS]
    #pragma unroll
    for (int j = 0; j < 4; ++j) {
        const int c = n0 + wcol * 64 + j * 16 + lr;      // output feature 0..2303
        const int which = c / 768;                        // 0=q 1=k 2=v (tile-uniform)
        const int rem = c - which * 768;
        const int h = rem >> 6, d = rem & 63;
        #pragma unroll
        for (int i = 0; i < 4; ++i)
            #pragma unroll
            for (int r = 0; r < 4; ++r) {
                const int row = m0 + wrow * 64 + i * 16 + lq * 4 + r;
                if (row >= MTOT) continue;
                const unsigned bb = (unsigned)row / 577u;
                const unsigned nn = (unsigned)row - bb * 577u;
                const _Float16 val = (_Float16)acc[i][j][r];
                const size_t head = (size_t)(bb * 12 + h);
                if (which == 0)      qg[(head * 577 + nn) * 64 + d] = val;
                else if (which == 1) kg[(head * 577 + nn) * 64 + d] = val;
                else                 vT[(head * 64 + d) * VTS + nn] = val;
            }
    }
}

// ---------------- flash attention: per (b,h,qtile64) block, 4 waves ---------
__global__ __launch_bounds__(256) void attn_kernel(const _Float16* __restrict__ qg,
                                                   const _Float16* __restrict__ kg,
                                                   const _Float16* __restrict__ vT,
                                                   const float* __restrict__ scale,
                                                   _Float16* __restrict__ Og) {
    __shared__ _Float16 Ks[64][72];   // K tile  [j][d], 144B stride
    __shared__ _Float16 Vs[64][72];   // V^T tile [d][j]
    __shared__ _Float16 Ps[64][72];   // P round-trip [i][j]
    const int qt = blockIdx.x, h = blockIdx.y, b = blockIdx.z;
    const int tid = threadIdx.x, lane = tid & 63, wv = tid >> 6;
    const int lr = lane & 15, lq = lane >> 4;
    const size_t head = (size_t)(b * 12 + h);
    const _Float16* qh = qg + head * 577 * 64;
    const _Float16* kh = kg + head * 577 * 64;
    const _Float16* vh = vT + head * 64 * VTS;
    const float sc = scale[h];
    const int q0 = qt * 64;

    const int qi = q0 + wv * 16 + lr;
    const int qc = qi < 577 ? qi : 576;          // clamp; invalid rows never stored
    const half8 aq0 = *(const half8*)(qh + (size_t)qc * 64 + lq * 8);
    const half8 aq1 = *(const half8*)(qh + (size_t)qc * 64 + 32 + lq * 8);

    const floatx4 fz = {0.f, 0.f, 0.f, 0.f};
    floatx4 o[4];
    for (int ct = 0; ct < 4; ++ct) o[ct] = fz;
    float m_i[4], l_i[4];
    for (int r = 0; r < 4; ++r) { m_i[r] = -INFINITY; l_i[r] = 0.f; }

    for (int kt = 0; kt < 10; ++kt) {
        const int j0 = kt * 64;
        __syncthreads();
        #pragma unroll
        for (int c = tid; c < 512; c += 256) {
            const int r = c >> 3, ch = c & 7;
            const int j = j0 + r;
            half8 v = {};
            if (j < 577) v = *(const half8*)(kh + (size_t)j * 64 + ch * 8);
            *(half8*)&Ks[r][ch * 8] = v;
        }
        #pragma unroll
        for (int c = tid; c < 512; c += 256) {
            const int d = c >> 3, ch = c & 7;
            const int nbase = j0 + ch * 8;
            half8 v = {};
            if (nbase < 577) {
                v = *(const half8*)(vh + (size_t)d * VTS + nbase);
                if (nbase + 8 > 577) {
                    #pragma unroll
                    for (int t = 0; t < 8; ++t)
                        if (nbase + t >= 577) v[t] = (_Float16)0;
                }
            }
            *(half8*)&Vs[d][ch * 8] = v;
        }
        __syncthreads();

        floatx4 s[4];
        #pragma unroll
        for (int ct = 0; ct < 4; ++ct) {
            const half8 b0 = *(const half8*)&Ks[ct * 16 + lr][lq * 8];
            const half8 b1 = *(const half8*)&Ks[ct * 16 + lr][32 + lq * 8];
            floatx4 t = fz;
            t = __builtin_amdgcn_mfma_f32_16x16x32_f16(aq0, b0, t, 0, 0, 0);
            t = __builtin_amdgcn_mfma_f32_16x16x32_f16(aq1, b1, t, 0, 0, 0);
            s[ct] = t;
        }

        float mt[4];
        #pragma unroll
        for (int r = 0; r < 4; ++r) {
            const int i = q0 + wv * 16 + lq * 4 + r;
            #pragma unroll
            for (int ct = 0; ct < 4; ++ct) {
                const int j = j0 + ct * 16 + lr;
                float val = s[ct][r] * sc;
                if (i == j) val = NEG_V;
                if (j >= 577) val = -INFINITY;
                s[ct][r] = val;
            }
            mt[r] = fmaxf(fmaxf(s[0][r], s[1][r]), fmaxf(s[2][r], s[3][r]));
        }
        #pragma unroll
        for (int off = 1; off < 16; off <<= 1)
            #pragma unroll
            for (int r = 0; r < 4; ++r) mt[r] = fmaxf(mt[r], __shfl_xor(mt[r], off, 64));

        float alpha[4], rs[4];
        #pragma unroll
        for (int r = 0; r < 4; ++r) {
            const float mn = fmaxf(m_i[r], mt[r]);
            alpha[r] = __expf(m_i[r] - mn);
            m_i[r] = mn;
            rs[r] = 0.f;
        }
        #pragma unroll
        for (int ct = 0; ct < 4; ++ct)
            #pragma unroll
            for (int r = 0; r < 4; ++r) {
                const float p = __expf(s[ct][r] - m_i[r]);
                s[ct][r] = p;
                rs[r] += p;
            }
        #pragma unroll
        for (int off = 1; off < 16; off <<= 1)
            #pragma unroll
            for (int r = 0; r < 4; ++r) rs[r] += __shfl_xor(rs[r], off, 64);
        #pragma unroll
        for (int r = 0; r < 4; ++r) l_i[r] = l_i[r] * alpha[r] + rs[r];

        #pragma unroll
        for (int ct = 0; ct < 4; ++ct)
            #pragma unroll
            for (int r = 0; r < 4; ++r) {
                Ps[wv * 16 + lq * 4 + r][ct * 16 + lr] = (_Float16)s[ct][r];
                o[ct][r] *= alpha[r];
            }

        const half8 ap0 = *(const half8*)&Ps[wv * 16 + lr][lq * 8];
        const half8 ap1 = *(const half8*)&Ps[wv * 16 + lr][32 + lq * 8];
        #pragma unroll
        for (int ct = 0; ct < 4; ++ct) {
            const half8 b0 = *(const half8*)&Vs[ct * 16 + lr][lq * 8];
            const half8 b1 = *(const half8*)&Vs[ct * 16 + lr][32 + lq * 8];
            o[ct] = __builtin_amdgcn_mfma_f32_16x16x32_f16(ap0, b0, o[ct], 0, 0, 0);
            o[ct] = __builtin_amdgcn_mfma_f32_16x16x32_f16(ap1, b1, o[ct], 0, 0, 0);
        }
    }

    #pragma unroll
    for (int ct = 0; ct < 4; ++ct)
        #pragma unroll
        for (int r = 0; r < 4; ++r) {
            const int i = q0 + wv * 16 + lq * 4 + r;
            if (i < 577) {
                const float val = o[ct][r] / l_i[r];
                Og[((size_t)(b * 577 + i)) * 768 + h * 64 + ct * 16 + lr] = (_Float16)val;
            }
        }
}

// ---------------- GEMM2: out = O @ W_out + b_out (fp32 out) -----------------
__global__ __launch_bounds__(256) void gemm_out(const _Float16* __restrict__ Og,
                                                const _Float16* __restrict__ wT,
                                                const float* __restrict__ bias,
                                                float* __restrict__ out) {
    __shared__ _Float16 As[128 * 32];
    __shared__ _Float16 Bs[128 * 32];
    const int m0 = blockIdx.x * 128, n0 = blockIdx.y * 128;
    const int tid = threadIdx.x;
    const int lane = tid & 63, wv = tid >> 6;
    const int wrow = wv >> 1, wcol = wv & 1;
    const int lr = lane & 15, lq = lane >> 4;

    floatx4 acc[4][4];
    const floatx4 fz = {0.f, 0.f, 0.f, 0.f};
    for (int i = 0; i < 4; ++i)
        for (int j = 0; j < 4; ++j) acc[i][j] = fz;

    for (int kk = 0; kk < 768; kk += 32) {
        __syncthreads();
        #pragma unroll
        for (int t = 0; t < 2; ++t) {
            const int c = wv * 64 + t * 256 + lane;
            const int r = c >> 2, ch = c & 3;
            gl_lds16(Og + (size_t)(m0 + r) * 768 + kk + ch * 8,
                     As + (wv * 64 + t * 256) * 8);
            gl_lds16(wT + (size_t)(n0 + r) * 768 + kk + ch * 8,
                     Bs + (wv * 64 + t * 256) * 8);
        }
        __syncthreads();
        half8 af[4], bf[4];
        #pragma unroll
        for (int i = 0; i < 4; ++i)
            af[i] = *(const half8*)&As[(wrow * 64 + i * 16 + lr) * 32 + lq * 8];
        #pragma unroll
        for (int j = 0; j < 4; ++j)
            bf[j] = *(const half8*)&Bs[(wcol * 64 + j * 16 + lr) * 32 + lq * 8];
        #pragma unroll
        for (int i = 0; i < 4; ++i)
            #pragma unroll
            for (int j = 0; j < 4; ++j)
                acc[i][j] = __builtin_amdgcn_mfma_f32_16x16x32_f16(af[i], bf[j], acc[i][j], 0, 0, 0);
    }

    #pragma unroll
    for (int j = 0; j < 4; ++j) {
        const int c = n0 + wcol * 64 + j * 16 + lr;
        const float bv = bias[c];
        #pragma unroll
        for (int i = 0; i < 4; ++i)
            #pragma unroll
            for (int r = 0; r < 4; ++r) {
                const int row = m0 + wrow * 64 + i * 16 + lq * 4 + r;
                if (row < MTOT) out[(size_t)row * 768 + c] = acc[i][j][r] + bv;
            }
    }
}

// ---------------------------------------------------------------------------
extern "C" void kernel_launch(void* const* d_in, const int* in_sizes, int n_in,
                              void* d_out, int out_size, void* d_ws, size_t ws_size,
                              hipStream_t stream) {
    const float* x      = (const float*)d_in[0];   // [32,577,768]
    const float* W_qkv  = (const float*)d_in[1];   // [768,2304]
    const float* scale  = (const float*)d_in[2];   // [12]
    const float* W_out  = (const float*)d_in[3];   // [768,768]
    const float* b_out  = (const float*)d_in[4];   // [768]
    float* out = (float*)d_out;

    // workspace (f16), Og aliases x16 (x16 dead after gemm_qkv; WAR stream-safe):
    //   x16/Og [18560,768]  28,508,160 B
    //   q  [32,12,577,64]   28,360,704 B
    //   k  [32,12,577,64]   28,360,704 B
    //   vT [32,12,64,584]   28,704,768 B
    //   WqkvT [2304,768]     3,538,944 B
    //   WoutT [768,768]      1,179,648 B    total ~118.7 MB
    char* ws = (char*)d_ws;
    _Float16* x16   = (_Float16*)(ws);
    _Float16* Og    = x16;
    _Float16* qg    = (_Float16*)(ws + 28508160u);
    _Float16* kg    = (_Float16*)(ws + 28508160u + 28360704u);
    _Float16* vT    = (_Float16*)(ws + 28508160u + 2u * 28360704u);
    _Float16* WqkvT = (_Float16*)(ws + 28508160u + 2u * 28360704u + 28704768u);
    _Float16* WoutT = WqkvT + (size_t)2304 * 768;

    cvt_x<<<6960, 256, 0, stream>>>(x, x16);
    transpose_w<<<dim3(72, 24), 256, 0, stream>>>(W_qkv, WqkvT, 768, 2304);
    transpose_w<<<dim3(24, 24), 256, 0, stream>>>(W_out, WoutT, 768, 768);
    gemm_qkv<<<dim3(145, 18), 256, 0, stream>>>(x16, WqkvT, qg, kg, vT);
    attn_kernel<<<dim3(10, 12, 32), 256, 0, stream>>>(qg, kg, vT, scale, Og);
    gemm_out<<<dim3(145, 6), 256, 0, stream>>>(Og, WoutT, b_out, out);
}

// Round 4
// 387.512 us; speedup vs baseline: 1.5881x; 1.2247x over previous
//
#include <hip/hip_runtime.h>

// ---------------------------------------------------------------------------
// Attention (LSA, ViT-style) for MI355X / gfx950.
// B=32, N=577, DIM=768, H=12, DH=64. f16 MFMA, fp32 accumulate.
// cvt x->f16 | transpose W -> QKV GEMM (global_load_lds; q pre-scaled by
// scale[h]*log2e) -> flash attn (no-max exp2 softmax, S^T trick, register P)
// -> out-proj GEMM (+bias, fp32 out).
// ---------------------------------------------------------------------------

typedef _Float16 half8  __attribute__((ext_vector_type(8)));
typedef _Float16 h4f    __attribute__((ext_vector_type(4)));
typedef __fp16   hv2    __attribute__((ext_vector_type(2)));   // builtin-native half vecs
typedef __fp16   hv4    __attribute__((ext_vector_type(4)));
typedef float    floatx4 __attribute__((ext_vector_type(4)));

#define MTOT   18464          // B*N = 32*577
#define NEG_V  (-987654321.0f)
#define VTS    584            // padded row stride for V^T (multiple of 8)

// async 16B global->LDS (LDS dst = wave-uniform base + lane*16B)
__device__ __forceinline__ void gl_lds16(const _Float16* g, _Float16* l) {
    __builtin_amdgcn_global_load_lds(
        (const __attribute__((address_space(1))) unsigned int*)g,
        (__attribute__((address_space(3))) unsigned int*)l,
        16, 0, 0);
}

// ---------------- x fp32 -> f16, padded+zero-filled to 18560 rows -----------
__global__ __launch_bounds__(256) void cvt_x(const float* __restrict__ x,
                                             _Float16* __restrict__ x16) {
    const size_t idx = ((size_t)blockIdx.x * 256 + threadIdx.x) * 8;
    half8 h = {};
    if (idx < (size_t)MTOT * 768) {
        float4 a = *(const float4*)(x + idx);
        float4 b = *(const float4*)(x + idx + 4);
        h[0] = (_Float16)a.x; h[1] = (_Float16)a.y;
        h[2] = (_Float16)a.z; h[3] = (_Float16)a.w;
        h[4] = (_Float16)b.x; h[5] = (_Float16)b.y;
        h[6] = (_Float16)b.z; h[7] = (_Float16)b.w;
    }
    *(half8*)(x16 + idx) = h;
}

// ---------------- weight transpose: src[K][Ncol] f32 -> dst[Ncol][K] f16 ----
__global__ __launch_bounds__(256) void transpose_w(const float* __restrict__ src,
                                                   _Float16* __restrict__ dst,
                                                   int K, int Ncol) {
    __shared__ float tile[32][33];
    const int n0 = blockIdx.x * 32, k0 = blockIdx.y * 32;
    const int tx = threadIdx.x & 31, ty = threadIdx.x >> 5;   // 32 x 8
    for (int i = 0; i < 32; i += 8)
        tile[ty + i][tx] = src[(size_t)(k0 + ty + i) * Ncol + (n0 + tx)];
    __syncthreads();
    for (int i = 0; i < 32; i += 8)
        dst[(size_t)(n0 + ty + i) * K + (k0 + tx)] = (_Float16)tile[tx][ty + i];
}

// ---------------- GEMM1: qkv = x16 @ W_qkv^T, scatter to q,k,v^T (f16) ------
// q outputs are pre-multiplied by scale[h]*log2(e) so attention uses exp2.
__global__ __launch_bounds__(256) void gemm_qkv(const _Float16* __restrict__ x16,
                                                const _Float16* __restrict__ wT,
                                                const float* __restrict__ scale,
                                                _Float16* __restrict__ qg,
                                                _Float16* __restrict__ kg,
                                                _Float16* __restrict__ vT) {
    __shared__ _Float16 As[128 * 32];
    __shared__ _Float16 Bs[128 * 32];
    const int m0 = blockIdx.x * 128, n0 = blockIdx.y * 128;
    const int tid = threadIdx.x;
    const int lane = tid & 63, wv = tid >> 6;
    const int wrow = wv >> 1, wcol = wv & 1;
    const int lr = lane & 15, lq = lane >> 4;

    floatx4 acc[4][4];
    const floatx4 fz = {0.f, 0.f, 0.f, 0.f};
    for (int i = 0; i < 4; ++i)
        for (int j = 0; j < 4; ++j) acc[i][j] = fz;

    for (int kk = 0; kk < 768; kk += 32) {
        __syncthreads();
        #pragma unroll
        for (int t = 0; t < 2; ++t) {
            const int c = wv * 64 + t * 256 + lane;
            const int r = c >> 2, ch = c & 3;
            gl_lds16(x16 + (size_t)(m0 + r) * 768 + kk + ch * 8,
                     As + (wv * 64 + t * 256) * 8);
            gl_lds16(wT + (size_t)(n0 + r) * 768 + kk + ch * 8,
                     Bs + (wv * 64 + t * 256) * 8);
        }
        __syncthreads();
        half8 af[4], bf[4];
        #pragma unroll
        for (int i = 0; i < 4; ++i)
            af[i] = *(const half8*)&As[(wrow * 64 + i * 16 + lr) * 32 + lq * 8];
        #pragma unroll
        for (int j = 0; j < 4; ++j)
            bf[j] = *(const half8*)&Bs[(wcol * 64 + j * 16 + lr) * 32 + lq * 8];
        #pragma unroll
        for (int i = 0; i < 4; ++i)
            #pragma unroll
            for (int j = 0; j < 4; ++j)
                acc[i][j] = __builtin_amdgcn_mfma_f32_16x16x32_f16(af[i], bf[j], acc[i][j], 0, 0, 0);
    }

    #pragma unroll
    for (int j = 0; j < 4; ++j) {
        const int c = n0 + wcol * 64 + j * 16 + lr;      // output feature 0..2303
        const int which = c / 768;                        // 0=q 1=k 2=v (tile-uniform)
        const int rem = c - which * 768;
        const int h = rem >> 6, d = rem & 63;
        const float qsc = (which == 0) ? scale[h] * 1.4426950408889634f : 1.0f;
        #pragma unroll
        for (int i = 0; i < 4; ++i)
            #pragma unroll
            for (int r = 0; r < 4; ++r) {
                const int row = m0 + wrow * 64 + i * 16 + lq * 4 + r;
                if (row >= MTOT) continue;
                const unsigned bb = (unsigned)row / 577u;
                const unsigned nn = (unsigned)row - bb * 577u;
                const _Float16 val = (_Float16)(acc[i][j][r] * qsc);
                const size_t head = (size_t)(bb * 12 + h);
                if (which == 0)      qg[(head * 577 + nn) * 64 + d] = val;
                else if (which == 1) kg[(head * 577 + nn) * 64 + d] = val;
                else                 vT[(head * 64 + d) * VTS + nn] = val;
            }
    }
}

// ---------------- flash attention v2: per (b,h,qtile128) block, 4 waves -----
// No-max softmax (exp2; scale*log2e pre-folded into Q). S^T orientation:
// S^T = MFMA(A=K,B=Q) -> C-layout(i=lane&15, j=quad*4+r) == K=16 B-operand
// layout for P, so PV = MFMA(A=V^T frag, B=packed P) with NO LDS round-trip.
// K/V^T tiles staged via swizzled global_load_lds (16B chunk ^ (row&7)).
__global__ __launch_bounds__(256) void attn_kernel(const _Float16* __restrict__ qg,
                                                   const _Float16* __restrict__ kg,
                                                   const _Float16* __restrict__ vT,
                                                   _Float16* __restrict__ Og) {
    __shared__ __align__(16) _Float16 Ks[64 * 64];   // [j][d], swizzled chunks
    __shared__ __align__(16) _Float16 Vs[64 * 64];   // [d][j], swizzled chunks
    const int qt = blockIdx.x, h = blockIdx.y, b = blockIdx.z;
    const int tid = threadIdx.x, lane = tid & 63, wv = tid >> 6;
    const int lr = lane & 15, lq = lane >> 4;
    const size_t head = (size_t)(b * 12 + h);
    const _Float16* qh = qg + head * 577 * 64;
    const _Float16* kh = kg + head * 577 * 64;
    const _Float16* vh = vT + head * 64 * VTS;
    const int q0 = qt * 128;
    const int xs = lq ^ (lr & 7), xs4 = xs ^ 4;      // swizzled b128 chunks

    // Q B-fragments per strip (pre-scaled by scale*log2e in gemm_qkv)
    half8 bq[2][2];
    #pragma unroll
    for (int st = 0; st < 2; ++st) {
        const int qi = q0 + st * 64 + wv * 16 + lr;
        const int qc = qi < 577 ? qi : 576;          // clamp; never stored
        bq[st][0] = *(const half8*)(qh + (size_t)qc * 64 + lq * 8);
        bq[st][1] = *(const half8*)(qh + (size_t)qc * 64 + 32 + lq * 8);
    }

    const floatx4 fz = {0.f, 0.f, 0.f, 0.f};
    floatx4 ot[2][4];                                 // O^T acc
    #pragma unroll
    for (int st = 0; st < 2; ++st)
        #pragma unroll
        for (int c = 0; c < 4; ++c) ot[st][c] = fz;
    float sacc[2] = {0.f, 0.f};

    for (int kt = 0; kt < 10; ++kt) {
        const int j0 = kt * 64;
        __syncthreads();
        // stage K[j][d] and V^T[d][j] tiles, 16B chunks, chunk^=(row&7) swizzle
        #pragma unroll
        for (int t = 0; t < 2; ++t) {
            const int c = t * 256 + wv * 64 + lane;   // chunk 0..511
            const int row = c >> 3, cl = (c & 7) ^ (row & 7);
            gl_lds16(kh + (size_t)(j0 + row) * 64 + cl * 8,
                     Ks + (t * 256 + wv * 64) * 8);
            gl_lds16(vh + (size_t)row * VTS + j0 + cl * 8,
                     Vs + (t * 256 + wv * 64) * 8);
        }
        __syncthreads();

        // K A-fragments (shared by both strips)
        half8 ak[4][2];
        #pragma unroll
        for (int ct = 0; ct < 4; ++ct) {
            const int base = (ct * 16 + lr) * 64;
            ak[ct][0] = *(const half8*)&Ks[base + xs * 8];
            ak[ct][1] = *(const half8*)&Ks[base + xs4 * 8];
        }

        // S^T[j][i]: j = j0+ct*16+lq*4+r, i = q0+st*64+wv*16+lr
        floatx4 s[2][4];
        #pragma unroll
        for (int st = 0; st < 2; ++st)
            #pragma unroll
            for (int ct = 0; ct < 4; ++ct) {
                floatx4 t = __builtin_amdgcn_mfma_f32_16x16x32_f16(ak[ct][0], bq[st][0], fz, 0, 0, 0);
                s[st][ct] = __builtin_amdgcn_mfma_f32_16x16x32_f16(ak[ct][1], bq[st][1], t, 0, 0, 0);
            }

        // pad mask: only col j=576 (ct=0,lq=0,r=0) survives tile 9
        if (kt == 9) {
            #pragma unroll
            for (int st = 0; st < 2; ++st) {
                s[st][0][0] = (lq == 0) ? s[st][0][0] : -INFINITY;
                s[st][0][1] = -INFINITY; s[st][0][2] = -INFINITY; s[st][0][3] = -INFINITY;
                #pragma unroll
                for (int ct = 1; ct < 4; ++ct) {
                    s[st][ct][0] = -INFINITY; s[st][ct][1] = -INFINITY;
                    s[st][ct][2] = -INFINITY; s[st][ct][3] = -INFINITY;
                }
            }
        }
        // diagonal mask: tile kt == qt*2+st, block ct==wv, lq*4+r == lr
        #pragma unroll
        for (int st = 0; st < 2; ++st) {
            if (kt == qt * 2 + st) {
                #pragma unroll
                for (int ct = 0; ct < 4; ++ct)
                    if (ct == wv) {
                        #pragma unroll
                        for (int r = 0; r < 4; ++r)
                            if (lq * 4 + r == lr) s[st][ct][r] = -INFINITY;
                    }
            }
        }

        // exp2 + deferred row-sum + pack to f16 (register P, K=16 B-operand)
        hv4 pk[2][4];
        #pragma unroll
        for (int st = 0; st < 2; ++st)
            #pragma unroll
            for (int ct = 0; ct < 4; ++ct) {
                const float p0 = __builtin_amdgcn_exp2f(s[st][ct][0]);
                const float p1 = __builtin_amdgcn_exp2f(s[st][ct][1]);
                const float p2 = __builtin_amdgcn_exp2f(s[st][ct][2]);
                const float p3 = __builtin_amdgcn_exp2f(s[st][ct][3]);
                sacc[st] += (p0 + p1) + (p2 + p3);
                const hv2 lo = __builtin_amdgcn_cvt_pkrtz(p0, p1);
                const hv2 hi = __builtin_amdgcn_cvt_pkrtz(p2, p3);
                pk[st][ct] = __builtin_shufflevector(lo, hi, 0, 1, 2, 3);
            }

        // O^T += V^T * P : A = V^T[d=ctd*16+lr][j chunk], B = pk[jc]
        #pragma unroll
        for (int jc = 0; jc < 4; ++jc) {
            const int csv = ((jc << 1) | (lq >> 1)) ^ (lr & 7);
            #pragma unroll
            for (int ctd = 0; ctd < 4; ++ctd) {
                const hv4 av = *(const hv4*)&Vs[(ctd * 16 + lr) * 64 + csv * 8 + (lq & 1) * 4];
                #pragma unroll
                for (int st = 0; st < 2; ++st)
                    ot[st][ctd] = __builtin_amdgcn_mfma_f32_16x16x16f16(av, pk[st][jc], ot[st][ctd], 0, 0, 0);
            }
        }
    }

    // epilogue: reduce row sums across quads, normalize, store O (f16)
    #pragma unroll
    for (int st = 0; st < 2; ++st) {
        float l = sacc[st];
        l += __shfl_xor(l, 16, 64);
        l += __shfl_xor(l, 32, 64);
        const float linv = 1.f / l;
        const int i = q0 + st * 64 + wv * 16 + lr;
        if (i < 577) {
            #pragma unroll
            for (int ctd = 0; ctd < 4; ++ctd) {
                h4f ov;
                #pragma unroll
                for (int r = 0; r < 4; ++r) ov[r] = (_Float16)(ot[st][ctd][r] * linv);
                *(h4f*)(Og + ((size_t)(b * 577 + i)) * 768 + h * 64 + ctd * 16 + lq * 4) = ov;
            }
        }
    }
}

// ---------------- GEMM2: out = O @ W_out + b_out (fp32 out) -----------------
__global__ __launch_bounds__(256) void gemm_out(const _Float16* __restrict__ Og,
                                                const _Float16* __restrict__ wT,
                                                const float* __restrict__ bias,
                                                float* __restrict__ out) {
    __shared__ _Float16 As[128 * 32];
    __shared__ _Float16 Bs[128 * 32];
    const int m0 = blockIdx.x * 128, n0 = blockIdx.y * 128;
    const int tid = threadIdx.x;
    const int lane = tid & 63, wv = tid >> 6;
    const int wrow = wv >> 1, wcol = wv & 1;
    const int lr = lane & 15, lq = lane >> 4;

    floatx4 acc[4][4];
    const floatx4 fz = {0.f, 0.f, 0.f, 0.f};
    for (int i = 0; i < 4; ++i)
        for (int j = 0; j < 4; ++j) acc[i][j] = fz;

    for (int kk = 0; kk < 768; kk += 32) {
        __syncthreads();
        #pragma unroll
        for (int t = 0; t < 2; ++t) {
            const int c = wv * 64 + t * 256 + lane;
            const int r = c >> 2, ch = c & 3;
            gl_lds16(Og + (size_t)(m0 + r) * 768 + kk + ch * 8,
                     As + (wv * 64 + t * 256) * 8);
            gl_lds16(wT + (size_t)(n0 + r) * 768 + kk + ch * 8,
                     Bs + (wv * 64 + t * 256) * 8);
        }
        __syncthreads();
        half8 af[4], bf[4];
        #pragma unroll
        for (int i = 0; i < 4; ++i)
            af[i] = *(const half8*)&As[(wrow * 64 + i * 16 + lr) * 32 + lq * 8];
        #pragma unroll
        for (int j = 0; j < 4; ++j)
            bf[j] = *(const half8*)&Bs[(wcol * 64 + j * 16 + lr) * 32 + lq * 8];
        #pragma unroll
        for (int i = 0; i < 4; ++i)
            #pragma unroll
            for (int j = 0; j < 4; ++j)
                acc[i][j] = __builtin_amdgcn_mfma_f32_16x16x32_f16(af[i], bf[j], acc[i][j], 0, 0, 0);
    }

    #pragma unroll
    for (int j = 0; j < 4; ++j) {
        const int c = n0 + wcol * 64 + j * 16 + lr;
        const float bv = bias[c];
        #pragma unroll
        for (int i = 0; i < 4; ++i)
            #pragma unroll
            for (int r = 0; r < 4; ++r) {
                const int row = m0 + wrow * 64 + i * 16 + lq * 4 + r;
                if (row < MTOT) out[(size_t)row * 768 + c] = acc[i][j][r] + bv;
            }
    }
}

// ---------------------------------------------------------------------------
extern "C" void kernel_launch(void* const* d_in, const int* in_sizes, int n_in,
                              void* d_out, int out_size, void* d_ws, size_t ws_size,
                              hipStream_t stream) {
    const float* x      = (const float*)d_in[0];   // [32,577,768]
    const float* W_qkv  = (const float*)d_in[1];   // [768,2304]
    const float* scale  = (const float*)d_in[2];   // [12]
    const float* W_out  = (const float*)d_in[3];   // [768,768]
    const float* b_out  = (const float*)d_in[4];   // [768]
    float* out = (float*)d_out;

    // workspace (f16), Og aliases x16 (x16 dead after gemm_qkv):
    //   x16/Og [18560,768]  28,508,160 B
    //   q  [32,12,577,64]   28,360,704 B
    //   k  [32,12,577,64]   28,360,704 B
    //   vT [32,12,64,584]   28,704,768 B
    //   WqkvT [2304,768]     3,538,944 B
    //   WoutT [768,768]      1,179,648 B    total ~118.7 MB
    char* ws = (char*)d_ws;
    _Float16* x16   = (_Float16*)(ws);
    _Float16* Og    = x16;
    _Float16* qg    = (_Float16*)(ws + 28508160u);
    _Float16* kg    = (_Float16*)(ws + 28508160u + 28360704u);
    _Float16* vT    = (_Float16*)(ws + 28508160u + 2u * 28360704u);
    _Float16* WqkvT = (_Float16*)(ws + 28508160u + 2u * 28360704u + 28704768u);
    _Float16* WoutT = WqkvT + (size_t)2304 * 768;

    cvt_x<<<6960, 256, 0, stream>>>(x, x16);
    transpose_w<<<dim3(72, 24), 256, 0, stream>>>(W_qkv, WqkvT, 768, 2304);
    transpose_w<<<dim3(24, 24), 256, 0, stream>>>(W_out, WoutT, 768, 768);
    gemm_qkv<<<dim3(145, 18), 256, 0, stream>>>(x16, WqkvT, scale, qg, kg, vT);
    attn_kernel<<<dim3(5, 12, 32), 256, 0, stream>>>(qg, kg, vT, Og);
    gemm_out<<<dim3(145, 6), 256, 0, stream>>>(Og, WoutT, b_out, out);
}

// Round 5
// 357.053 us; speedup vs baseline: 1.7236x; 1.0853x over previous
//
#include <hip/hip_runtime.h>

// ---------------------------------------------------------------------------
// Attention (LSA, ViT-style) for MI355X / gfx950.
// B=32, N=577, DIM=768, H=12, DH=64. f16 MFMA, fp32 accumulate.
// cvt x->f16 | transpose W -> QKV GEMM (128x256 tile, 8 waves, global_load_lds;
// q pre-scaled by scale[h]*log2e) -> flash attn (no-max exp2 softmax, S^T
// trick, register P) -> out-proj GEMM (128x256, +bias, fp32 out).
// ---------------------------------------------------------------------------

typedef _Float16 half8  __attribute__((ext_vector_type(8)));
typedef _Float16 h4f    __attribute__((ext_vector_type(4)));
typedef __fp16   hv2    __attribute__((ext_vector_type(2)));   // builtin-native half vecs
typedef __fp16   hv4    __attribute__((ext_vector_type(4)));
typedef float    floatx4 __attribute__((ext_vector_type(4)));

#define MTOT   18464          // B*N = 32*577
#define NEG_V  (-987654321.0f)
#define VTS    584            // padded row stride for V^T (multiple of 8)

// async 16B global->LDS (LDS dst = wave-uniform base + lane*16B)
__device__ __forceinline__ void gl_lds16(const _Float16* g, _Float16* l) {
    __builtin_amdgcn_global_load_lds(
        (const __attribute__((address_space(1))) unsigned int*)g,
        (__attribute__((address_space(3))) unsigned int*)l,
        16, 0, 0);
}

// ---------------- x fp32 -> f16, padded+zero-filled to 18560 rows -----------
__global__ __launch_bounds__(256) void cvt_x(const float* __restrict__ x,
                                             _Float16* __restrict__ x16) {
    const size_t idx = ((size_t)blockIdx.x * 256 + threadIdx.x) * 8;
    half8 h = {};
    if (idx < (size_t)MTOT * 768) {
        float4 a = *(const float4*)(x + idx);
        float4 b = *(const float4*)(x + idx + 4);
        h[0] = (_Float16)a.x; h[1] = (_Float16)a.y;
        h[2] = (_Float16)a.z; h[3] = (_Float16)a.w;
        h[4] = (_Float16)b.x; h[5] = (_Float16)b.y;
        h[6] = (_Float16)b.z; h[7] = (_Float16)b.w;
    }
    *(half8*)(x16 + idx) = h;
}

// ---------------- weight transpose: src[K][Ncol] f32 -> dst[Ncol][K] f16 ----
__global__ __launch_bounds__(256) void transpose_w(const float* __restrict__ src,
                                                   _Float16* __restrict__ dst,
                                                   int K, int Ncol) {
    __shared__ float tile[32][33];
    const int n0 = blockIdx.x * 32, k0 = blockIdx.y * 32;
    const int tx = threadIdx.x & 31, ty = threadIdx.x >> 5;   // 32 x 8
    for (int i = 0; i < 32; i += 8)
        tile[ty + i][tx] = src[(size_t)(k0 + ty + i) * Ncol + (n0 + tx)];
    __syncthreads();
    for (int i = 0; i < 32; i += 8)
        dst[(size_t)(n0 + ty + i) * K + (k0 + tx)] = (_Float16)tile[tx][ty + i];
}

// ---------------- GEMM1: qkv = x16 @ W_qkv^T, scatter to q,k,v^T (f16) ------
// 128x256 tile, 8 waves (2 row-pos x 4 col-pos, 64x64 each), BK=32.
// q outputs are pre-multiplied by scale[h]*log2(e) so attention uses exp2.
__global__ __launch_bounds__(512, 4) void gemm_qkv(const _Float16* __restrict__ x16,
                                                   const _Float16* __restrict__ wT,
                                                   const float* __restrict__ scale,
                                                   _Float16* __restrict__ qg,
                                                   _Float16* __restrict__ kg,
                                                   _Float16* __restrict__ vT) {
    __shared__ _Float16 As[128 * 32];    //  8 KB
    __shared__ _Float16 Bs[256 * 32];    // 16 KB
    const int m0 = blockIdx.x * 128, n0 = blockIdx.y * 256;
    const int tid = threadIdx.x;
    const int lane = tid & 63, wv = tid >> 6;        // 8 waves
    const int wrow = wv >> 2, wcol = wv & 3;         // 2 x 4
    const int lr = lane & 15, lq = lane >> 4;

    floatx4 acc[4][4];
    const floatx4 fz = {0.f, 0.f, 0.f, 0.f};
    for (int i = 0; i < 4; ++i)
        for (int j = 0; j < 4; ++j) acc[i][j] = fz;

    for (int kk = 0; kk < 768; kk += 32) {
        __syncthreads();
        // A: 512 chunks (1/thread); chunk c -> row c>>2, 8-f16 group c&3
        {
            const int c = tid, r = c >> 2, ch = c & 3;
            gl_lds16(x16 + (size_t)(m0 + r) * 768 + kk + ch * 8, As + wv * 64 * 8);
        }
        // B: 1024 chunks (2/thread)
        #pragma unroll
        for (int t = 0; t < 2; ++t) {
            const int c = t * 512 + tid, r = c >> 2, ch = c & 3;
            gl_lds16(wT + (size_t)(n0 + r) * 768 + kk + ch * 8,
                     Bs + (t * 512 + wv * 64) * 8);
        }
        __syncthreads();
        half8 af[4], bf[4];
        #pragma unroll
        for (int i = 0; i < 4; ++i)
            af[i] = *(const half8*)&As[(wrow * 64 + i * 16 + lr) * 32 + lq * 8];
        #pragma unroll
        for (int j = 0; j < 4; ++j)
            bf[j] = *(const half8*)&Bs[(wcol * 64 + j * 16 + lr) * 32 + lq * 8];
        #pragma unroll
        for (int i = 0; i < 4; ++i)
            #pragma unroll
            for (int j = 0; j < 4; ++j)
                acc[i][j] = __builtin_amdgcn_mfma_f32_16x16x32_f16(af[i], bf[j], acc[i][j], 0, 0, 0);
    }

    // epilogue: wave-uniform which/h (wave col-base is a multiple of 64)
    const int cbase = n0 + wcol * 64;
    const int which = cbase / 768;                    // 0=q 1=k 2=v
    const int h = (cbase - which * 768) >> 6;         // head (uniform)
    const float qsc = (which == 0) ? scale[h] * 1.4426950408889634f : 1.0f;
    #pragma unroll
    for (int j = 0; j < 4; ++j) {
        const int d = j * 16 + lr;                    // 0..63 within head
        #pragma unroll
        for (int i = 0; i < 4; ++i)
            #pragma unroll
            for (int r = 0; r < 4; ++r) {
                const int row = m0 + wrow * 64 + i * 16 + lq * 4 + r;
                if (row >= MTOT) continue;
                const unsigned bb = (unsigned)row / 577u;
                const unsigned nn = (unsigned)row - bb * 577u;
                const _Float16 val = (_Float16)(acc[i][j][r] * qsc);
                const size_t head = (size_t)(bb * 12 + h);
                if (which == 0)      qg[(head * 577 + nn) * 64 + d] = val;
                else if (which == 1) kg[(head * 577 + nn) * 64 + d] = val;
                else                 vT[(head * 64 + d) * VTS + nn] = val;
            }
    }
}

// ---------------- flash attention: per (b,h,qtile128) block, 4 waves --------
// No-max softmax (exp2; scale*log2e pre-folded into Q). S^T orientation:
// S^T = MFMA(A=K,B=Q) -> C-layout == K=16 B-operand layout for P, so
// PV = MFMA(A=V^T frag, B=packed P) with NO LDS round-trip.
__global__ __launch_bounds__(256) void attn_kernel(const _Float16* __restrict__ qg,
                                                   const _Float16* __restrict__ kg,
                                                   const _Float16* __restrict__ vT,
                                                   _Float16* __restrict__ Og) {
    __shared__ __align__(16) _Float16 Ks[64 * 64];   // [j][d], swizzled chunks
    __shared__ __align__(16) _Float16 Vs[64 * 64];   // [d][j], swizzled chunks
    const int qt = blockIdx.x, h = blockIdx.y, b = blockIdx.z;
    const int tid = threadIdx.x, lane = tid & 63, wv = tid >> 6;
    const int lr = lane & 15, lq = lane >> 4;
    const size_t head = (size_t)(b * 12 + h);
    const _Float16* qh = qg + head * 577 * 64;
    const _Float16* kh = kg + head * 577 * 64;
    const _Float16* vh = vT + head * 64 * VTS;
    const int q0 = qt * 128;
    const int xs = lq ^ (lr & 7), xs4 = xs ^ 4;      // swizzled b128 chunks

    half8 bq[2][2];
    #pragma unroll
    for (int st = 0; st < 2; ++st) {
        const int qi = q0 + st * 64 + wv * 16 + lr;
        const int qc = qi < 577 ? qi : 576;          // clamp; never stored
        bq[st][0] = *(const half8*)(qh + (size_t)qc * 64 + lq * 8);
        bq[st][1] = *(const half8*)(qh + (size_t)qc * 64 + 32 + lq * 8);
    }

    const floatx4 fz = {0.f, 0.f, 0.f, 0.f};
    floatx4 ot[2][4];
    #pragma unroll
    for (int st = 0; st < 2; ++st)
        #pragma unroll
        for (int c = 0; c < 4; ++c) ot[st][c] = fz;
    float sacc[2] = {0.f, 0.f};

    for (int kt = 0; kt < 10; ++kt) {
        const int j0 = kt * 64;
        __syncthreads();
        #pragma unroll
        for (int t = 0; t < 2; ++t) {
            const int c = t * 256 + wv * 64 + lane;   // chunk 0..511
            const int row = c >> 3, cl = (c & 7) ^ (row & 7);
            gl_lds16(kh + (size_t)(j0 + row) * 64 + cl * 8,
                     Ks + (t * 256 + wv * 64) * 8);
            gl_lds16(vh + (size_t)row * VTS + j0 + cl * 8,
                     Vs + (t * 256 + wv * 64) * 8);
        }
        __syncthreads();

        half8 ak[4][2];
        #pragma unroll
        for (int ct = 0; ct < 4; ++ct) {
            const int base = (ct * 16 + lr) * 64;
            ak[ct][0] = *(const half8*)&Ks[base + xs * 8];
            ak[ct][1] = *(const half8*)&Ks[base + xs4 * 8];
        }

        floatx4 s[2][4];
        #pragma unroll
        for (int st = 0; st < 2; ++st)
            #pragma unroll
            for (int ct = 0; ct < 4; ++ct) {
                floatx4 t = __builtin_amdgcn_mfma_f32_16x16x32_f16(ak[ct][0], bq[st][0], fz, 0, 0, 0);
                s[st][ct] = __builtin_amdgcn_mfma_f32_16x16x32_f16(ak[ct][1], bq[st][1], t, 0, 0, 0);
            }

        if (kt == 9) {
            #pragma unroll
            for (int st = 0; st < 2; ++st) {
                s[st][0][0] = (lq == 0) ? s[st][0][0] : -INFINITY;
                s[st][0][1] = -INFINITY; s[st][0][2] = -INFINITY; s[st][0][3] = -INFINITY;
                #pragma unroll
                for (int ct = 1; ct < 4; ++ct) {
                    s[st][ct][0] = -INFINITY; s[st][ct][1] = -INFINITY;
                    s[st][ct][2] = -INFINITY; s[st][ct][3] = -INFINITY;
                }
            }
        }
        #pragma unroll
        for (int st = 0; st < 2; ++st) {
            if (kt == qt * 2 + st) {
                #pragma unroll
                for (int ct = 0; ct < 4; ++ct)
                    if (ct == wv) {
                        #pragma unroll
                        for (int r = 0; r < 4; ++r)
                            if (lq * 4 + r == lr) s[st][ct][r] = -INFINITY;
                    }
            }
        }

        hv4 pk[2][4];
        #pragma unroll
        for (int st = 0; st < 2; ++st)
            #pragma unroll
            for (int ct = 0; ct < 4; ++ct) {
                const float p0 = __builtin_amdgcn_exp2f(s[st][ct][0]);
                const float p1 = __builtin_amdgcn_exp2f(s[st][ct][1]);
                const float p2 = __builtin_amdgcn_exp2f(s[st][ct][2]);
                const float p3 = __builtin_amdgcn_exp2f(s[st][ct][3]);
                sacc[st] += (p0 + p1) + (p2 + p3);
                const hv2 lo = __builtin_amdgcn_cvt_pkrtz(p0, p1);
                const hv2 hi = __builtin_amdgcn_cvt_pkrtz(p2, p3);
                pk[st][ct] = __builtin_shufflevector(lo, hi, 0, 1, 2, 3);
            }

        #pragma unroll
        for (int jc = 0; jc < 4; ++jc) {
            const int csv = ((jc << 1) | (lq >> 1)) ^ (lr & 7);
            #pragma unroll
            for (int ctd = 0; ctd < 4; ++ctd) {
                const hv4 av = *(const hv4*)&Vs[(ctd * 16 + lr) * 64 + csv * 8 + (lq & 1) * 4];
                #pragma unroll
                for (int st = 0; st < 2; ++st)
                    ot[st][ctd] = __builtin_amdgcn_mfma_f32_16x16x16f16(av, pk[st][jc], ot[st][ctd], 0, 0, 0);
            }
        }
    }

    #pragma unroll
    for (int st = 0; st < 2; ++st) {
        float l = sacc[st];
        l += __shfl_xor(l, 16, 64);
        l += __shfl_xor(l, 32, 64);
        const float linv = 1.f / l;
        const int i = q0 + st * 64 + wv * 16 + lr;
        if (i < 577) {
            #pragma unroll
            for (int ctd = 0; ctd < 4; ++ctd) {
                h4f ov;
                #pragma unroll
                for (int r = 0; r < 4; ++r) ov[r] = (_Float16)(ot[st][ctd][r] * linv);
                *(h4f*)(Og + ((size_t)(b * 577 + i)) * 768 + h * 64 + ctd * 16 + lq * 4) = ov;
            }
        }
    }
}

// ---------------- GEMM2: out = O @ W_out + b_out (fp32 out), 128x256 --------
__global__ __launch_bounds__(512, 4) void gemm_out(const _Float16* __restrict__ Og,
                                                   const _Float16* __restrict__ wT,
                                                   const float* __restrict__ bias,
                                                   float* __restrict__ out) {
    __shared__ _Float16 As[128 * 32];
    __shared__ _Float16 Bs[256 * 32];
    const int m0 = blockIdx.x * 128, n0 = blockIdx.y * 256;
    const int tid = threadIdx.x;
    const int lane = tid & 63, wv = tid >> 6;
    const int wrow = wv >> 2, wcol = wv & 3;
    const int lr = lane & 15, lq = lane >> 4;

    floatx4 acc[4][4];
    const floatx4 fz = {0.f, 0.f, 0.f, 0.f};
    for (int i = 0; i < 4; ++i)
        for (int j = 0; j < 4; ++j) acc[i][j] = fz;

    for (int kk = 0; kk < 768; kk += 32) {
        __syncthreads();
        {
            const int c = tid, r = c >> 2, ch = c & 3;
            gl_lds16(Og + (size_t)(m0 + r) * 768 + kk + ch * 8, As + wv * 64 * 8);
        }
        #pragma unroll
        for (int t = 0; t < 2; ++t) {
            const int c = t * 512 + tid, r = c >> 2, ch = c & 3;
            gl_lds16(wT + (size_t)(n0 + r) * 768 + kk + ch * 8,
                     Bs + (t * 512 + wv * 64) * 8);
        }
        __syncthreads();
        half8 af[4], bf[4];
        #pragma unroll
        for (int i = 0; i < 4; ++i)
            af[i] = *(const half8*)&As[(wrow * 64 + i * 16 + lr) * 32 + lq * 8];
        #pragma unroll
        for (int j = 0; j < 4; ++j)
            bf[j] = *(const half8*)&Bs[(wcol * 64 + j * 16 + lr) * 32 + lq * 8];
        #pragma unroll
        for (int i = 0; i < 4; ++i)
            #pragma unroll
            for (int j = 0; j < 4; ++j)
                acc[i][j] = __builtin_amdgcn_mfma_f32_16x16x32_f16(af[i], bf[j], acc[i][j], 0, 0, 0);
    }

    #pragma unroll
    for (int j = 0; j < 4; ++j) {
        const int c = n0 + wcol * 64 + j * 16 + lr;
        const float bv = bias[c];
        #pragma unroll
        for (int i = 0; i < 4; ++i)
            #pragma unroll
            for (int r = 0; r < 4; ++r) {
                const int row = m0 + wrow * 64 + i * 16 + lq * 4 + r;
                if (row < MTOT) out[(size_t)row * 768 + c] = acc[i][j][r] + bv;
            }
    }
}

// ---------------------------------------------------------------------------
extern "C" void kernel_launch(void* const* d_in, const int* in_sizes, int n_in,
                              void* d_out, int out_size, void* d_ws, size_t ws_size,
                              hipStream_t stream) {
    const float* x      = (const float*)d_in[0];   // [32,577,768]
    const float* W_qkv  = (const float*)d_in[1];   // [768,2304]
    const float* scale  = (const float*)d_in[2];   // [12]
    const float* W_out  = (const float*)d_in[3];   // [768,768]
    const float* b_out  = (const float*)d_in[4];   // [768]
    float* out = (float*)d_out;

    // workspace (f16), Og aliases x16 (x16 dead after gemm_qkv):
    //   x16/Og [18560,768]  28,508,160 B
    //   q  [32,12,577,64]   28,360,704 B
    //   k  [32,12,577,64]   28,360,704 B
    //   vT [32,12,64,584]   28,704,768 B
    //   WqkvT [2304,768]     3,538,944 B
    //   WoutT [768,768]      1,179,648 B    total ~118.7 MB
    char* ws = (char*)d_ws;
    _Float16* x16   = (_Float16*)(ws);
    _Float16* Og    = x16;
    _Float16* qg    = (_Float16*)(ws + 28508160u);
    _Float16* kg    = (_Float16*)(ws + 28508160u + 28360704u);
    _Float16* vT    = (_Float16*)(ws + 28508160u + 2u * 28360704u);
    _Float16* WqkvT = (_Float16*)(ws + 28508160u + 2u * 28360704u + 28704768u);
    _Float16* WoutT = WqkvT + (size_t)2304 * 768;

    cvt_x<<<6960, 256, 0, stream>>>(x, x16);
    transpose_w<<<dim3(72, 24), 256, 0, stream>>>(W_qkv, WqkvT, 768, 2304);
    transpose_w<<<dim3(24, 24), 256, 0, stream>>>(W_out, WoutT, 768, 768);
    gemm_qkv<<<dim3(145, 9), 512, 0, stream>>>(x16, WqkvT, scale, qg, kg, vT);
    attn_kernel<<<dim3(5, 12, 32), 256, 0, stream>>>(qg, kg, vT, Og);
    gemm_out<<<dim3(145, 3), 512, 0, stream>>>(Og, WoutT, b_out, out);
}

// Round 6
// 355.912 us; speedup vs baseline: 1.7291x; 1.0032x over previous
//
#include <hip/hip_runtime.h>

// ---------------------------------------------------------------------------
// Attention (LSA, ViT-style) for MI355X / gfx950.
// B=32, N=577, DIM=768, H=12, DH=64. f16 MFMA, fp32 accumulate.
// GEMMs: 128x256 tile, 8 waves, DOUBLE-BUFFERED global_load_lds pipeline with
// fine-grained s_waitcnt vmcnt(3) (prefetch stays in flight across barriers).
// Attn: no-max exp2 softmax, S^T trick, register-resident P.
// ---------------------------------------------------------------------------

typedef _Float16 half8  __attribute__((ext_vector_type(8)));
typedef _Float16 h4f    __attribute__((ext_vector_type(4)));
typedef __fp16   hv2    __attribute__((ext_vector_type(2)));
typedef __fp16   hv4    __attribute__((ext_vector_type(4)));
typedef float    floatx4 __attribute__((ext_vector_type(4)));

#define MTOT   18464          // B*N = 32*577
#define NEG_V  (-987654321.0f)
#define VTS    584            // padded row stride for V^T (multiple of 8)

// async 16B global->LDS (LDS dst = wave-uniform base + lane*16B)
__device__ __forceinline__ void gl_lds16(const _Float16* g, _Float16* l) {
    __builtin_amdgcn_global_load_lds(
        (const __attribute__((address_space(1))) unsigned int*)g,
        (__attribute__((address_space(3))) unsigned int*)l,
        16, 0, 0);
}

// ---------------- x fp32 -> f16, padded+zero-filled to 18560 rows -----------
__global__ __launch_bounds__(256) void cvt_x(const float* __restrict__ x,
                                             _Float16* __restrict__ x16) {
    const size_t idx = ((size_t)blockIdx.x * 256 + threadIdx.x) * 8;
    half8 h = {};
    if (idx < (size_t)MTOT * 768) {
        float4 a = *(const float4*)(x + idx);
        float4 b = *(const float4*)(x + idx + 4);
        h[0] = (_Float16)a.x; h[1] = (_Float16)a.y;
        h[2] = (_Float16)a.z; h[3] = (_Float16)a.w;
        h[4] = (_Float16)b.x; h[5] = (_Float16)b.y;
        h[6] = (_Float16)b.z; h[7] = (_Float16)b.w;
    }
    *(half8*)(x16 + idx) = h;
}

// ---------------- weight transpose: src[K][Ncol] f32 -> dst[Ncol][K] f16 ----
__global__ __launch_bounds__(256) void transpose_w(const float* __restrict__ src,
                                                   _Float16* __restrict__ dst,
                                                   int K, int Ncol) {
    __shared__ float tile[32][33];
    const int n0 = blockIdx.x * 32, k0 = blockIdx.y * 32;
    const int tx = threadIdx.x & 31, ty = threadIdx.x >> 5;   // 32 x 8
    for (int i = 0; i < 32; i += 8)
        tile[ty + i][tx] = src[(size_t)(k0 + ty + i) * Ncol + (n0 + tx)];
    __syncthreads();
    for (int i = 0; i < 32; i += 8)
        dst[(size_t)(n0 + ty + i) * K + (k0 + tx)] = (_Float16)tile[tx][ty + i];
}

// ---------------- GEMM1: qkv = x16 @ W_qkv^T, scatter to q,k,v^T (f16) ------
// 128x256 tile, 8 waves (2x4 of 64x64), BK=32, double-buffered DMA pipeline.
// q outputs pre-multiplied by scale[h]*log2(e) so attention uses exp2.
__global__ __launch_bounds__(512, 4) void gemm_qkv(const _Float16* __restrict__ x16,
                                                   const _Float16* __restrict__ wT,
                                                   const float* __restrict__ scale,
                                                   _Float16* __restrict__ qg,
                                                   _Float16* __restrict__ kg,
                                                   _Float16* __restrict__ vT) {
    __shared__ _Float16 As[2][128 * 32];    // 2 x  8 KB
    __shared__ _Float16 Bs[2][256 * 32];    // 2 x 16 KB   (48 KB total)
    const int m0 = blockIdx.x * 128, n0 = blockIdx.y * 256;
    const int tid = threadIdx.x;
    const int lane = tid & 63, wv = tid >> 6;        // 8 waves
    const int wrow = wv >> 2, wcol = wv & 3;         // 2 x 4
    const int lr = lane & 15, lq = lane >> 4;

    // per-thread DMA source offsets (row/chunk fixed; k advances)
    const int ra  = tid >> 2,            ca  = (tid & 3) * 8;           // A: 1 chunk
    const int rb0 = tid >> 2,            cb0 = (tid & 3) * 8;           // B: 2 chunks
    const int rb1 = (512 + tid) >> 2,    cb1 = (tid & 3) * 8;

    floatx4 acc[4][4];
    const floatx4 fz = {0.f, 0.f, 0.f, 0.f};
    for (int i = 0; i < 4; ++i)
        for (int j = 0; j < 4; ++j) acc[i][j] = fz;

    // stage K-slice ki into buffer bf (3 DMA per thread)
    #define STAGE_QKV(ki, bf)                                                     \
        do {                                                                      \
            const int kk_ = (ki) * 32;                                            \
            gl_lds16(x16 + (size_t)(m0 + ra) * 768 + kk_ + ca, &As[bf][wv*64*8]); \
            gl_lds16(wT + (size_t)(n0 + rb0) * 768 + kk_ + cb0, &Bs[bf][wv*64*8]);\
            gl_lds16(wT + (size_t)(n0 + rb1) * 768 + kk_ + cb1,                   \
                     &Bs[bf][(512 + wv*64) * 8]);                                 \
        } while (0)

    STAGE_QKV(0, 0);
    for (int ki = 0; ki < 24; ++ki) {
        const int bf = ki & 1;
        if (ki < 23) {
            STAGE_QKV(ki + 1, bf ^ 1);
            asm volatile("s_waitcnt vmcnt(3)" ::: "memory");   // iter-k loads done; k+1 in flight
        } else {
            asm volatile("s_waitcnt vmcnt(0)" ::: "memory");
        }
        asm volatile("s_barrier" ::: "memory");

        half8 af[4], bfr[4];
        #pragma unroll
        for (int i = 0; i < 4; ++i)
            af[i] = *(const half8*)&As[bf][(wrow * 64 + i * 16 + lr) * 32 + lq * 8];
        #pragma unroll
        for (int j = 0; j < 4; ++j)
            bfr[j] = *(const half8*)&Bs[bf][(wcol * 64 + j * 16 + lr) * 32 + lq * 8];
        #pragma unroll
        for (int i = 0; i < 4; ++i)
            #pragma unroll
            for (int j = 0; j < 4; ++j)
                acc[i][j] = __builtin_amdgcn_mfma_f32_16x16x32_f16(af[i], bfr[j], acc[i][j], 0, 0, 0);

        // WAR: all waves' ds_reads retired before next iter's DMA overwrites
        asm volatile("s_waitcnt lgkmcnt(0)\n\ts_barrier" ::: "memory");
    }
    #undef STAGE_QKV

    // epilogue: wave-uniform which/h (wave col-base is a multiple of 64)
    const int cbase = n0 + wcol * 64;
    const int which = cbase / 768;                    // 0=q 1=k 2=v
    const int h = (cbase - which * 768) >> 6;         // head (uniform)
    const float qsc = (which == 0) ? scale[h] * 1.4426950408889634f : 1.0f;
    #pragma unroll
    for (int j = 0; j < 4; ++j) {
        const int d = j * 16 + lr;                    // 0..63 within head
        #pragma unroll
        for (int i = 0; i < 4; ++i)
            #pragma unroll
            for (int r = 0; r < 4; ++r) {
                const int row = m0 + wrow * 64 + i * 16 + lq * 4 + r;
                if (row >= MTOT) continue;
                const unsigned bb = (unsigned)row / 577u;
                const unsigned nn = (unsigned)row - bb * 577u;
                const _Float16 val = (_Float16)(acc[i][j][r] * qsc);
                const size_t head = (size_t)(bb * 12 + h);
                if (which == 0)      qg[(head * 577 + nn) * 64 + d] = val;
                else if (which == 1) kg[(head * 577 + nn) * 64 + d] = val;
                else                 vT[(head * 64 + d) * VTS + nn] = val;
            }
    }
}

// ---------------- flash attention: per (b,h,qtile128) block, 4 waves --------
__global__ __launch_bounds__(256) void attn_kernel(const _Float16* __restrict__ qg,
                                                   const _Float16* __restrict__ kg,
                                                   const _Float16* __restrict__ vT,
                                                   _Float16* __restrict__ Og) {
    __shared__ __align__(16) _Float16 Ks[64 * 64];   // [j][d], swizzled chunks
    __shared__ __align__(16) _Float16 Vs[64 * 64];   // [d][j], swizzled chunks
    const int qt = blockIdx.x, h = blockIdx.y, b = blockIdx.z;
    const int tid = threadIdx.x, lane = tid & 63, wv = tid >> 6;
    const int lr = lane & 15, lq = lane >> 4;
    const size_t head = (size_t)(b * 12 + h);
    const _Float16* qh = qg + head * 577 * 64;
    const _Float16* kh = kg + head * 577 * 64;
    const _Float16* vh = vT + head * 64 * VTS;
    const int q0 = qt * 128;
    const int xs = lq ^ (lr & 7), xs4 = xs ^ 4;      // swizzled b128 chunks

    half8 bq[2][2];
    #pragma unroll
    for (int st = 0; st < 2; ++st) {
        const int qi = q0 + st * 64 + wv * 16 + lr;
        const int qc = qi < 577 ? qi : 576;          // clamp; never stored
        bq[st][0] = *(const half8*)(qh + (size_t)qc * 64 + lq * 8);
        bq[st][1] = *(const half8*)(qh + (size_t)qc * 64 + 32 + lq * 8);
    }

    const floatx4 fz = {0.f, 0.f, 0.f, 0.f};
    floatx4 ot[2][4];
    #pragma unroll
    for (int st = 0; st < 2; ++st)
        #pragma unroll
        for (int c = 0; c < 4; ++c) ot[st][c] = fz;
    float sacc[2] = {0.f, 0.f};

    for (int kt = 0; kt < 10; ++kt) {
        const int j0 = kt * 64;
        __syncthreads();
        #pragma unroll
        for (int t = 0; t < 2; ++t) {
            const int c = t * 256 + wv * 64 + lane;   // chunk 0..511
            const int row = c >> 3, cl = (c & 7) ^ (row & 7);
            gl_lds16(kh + (size_t)(j0 + row) * 64 + cl * 8,
                     Ks + (t * 256 + wv * 64) * 8);
            gl_lds16(vh + (size_t)row * VTS + j0 + cl * 8,
                     Vs + (t * 256 + wv * 64) * 8);
        }
        __syncthreads();

        half8 ak[4][2];
        #pragma unroll
        for (int ct = 0; ct < 4; ++ct) {
            const int base = (ct * 16 + lr) * 64;
            ak[ct][0] = *(const half8*)&Ks[base + xs * 8];
            ak[ct][1] = *(const half8*)&Ks[base + xs4 * 8];
        }

        floatx4 s[2][4];
        #pragma unroll
        for (int st = 0; st < 2; ++st)
            #pragma unroll
            for (int ct = 0; ct < 4; ++ct) {
                floatx4 t = __builtin_amdgcn_mfma_f32_16x16x32_f16(ak[ct][0], bq[st][0], fz, 0, 0, 0);
                s[st][ct] = __builtin_amdgcn_mfma_f32_16x16x32_f16(ak[ct][1], bq[st][1], t, 0, 0, 0);
            }

        if (kt == 9) {
            #pragma unroll
            for (int st = 0; st < 2; ++st) {
                s[st][0][0] = (lq == 0) ? s[st][0][0] : -INFINITY;
                s[st][0][1] = -INFINITY; s[st][0][2] = -INFINITY; s[st][0][3] = -INFINITY;
                #pragma unroll
                for (int ct = 1; ct < 4; ++ct) {
                    s[st][ct][0] = -INFINITY; s[st][ct][1] = -INFINITY;
                    s[st][ct][2] = -INFINITY; s[st][ct][3] = -INFINITY;
                }
            }
        }
        #pragma unroll
        for (int st = 0; st < 2; ++st) {
            if (kt == qt * 2 + st) {
                #pragma unroll
                for (int ct = 0; ct < 4; ++ct)
                    if (ct == wv) {
                        #pragma unroll
                        for (int r = 0; r < 4; ++r)
                            if (lq * 4 + r == lr) s[st][ct][r] = -INFINITY;
                    }
            }
        }

        hv4 pk[2][4];
        #pragma unroll
        for (int st = 0; st < 2; ++st)
            #pragma unroll
            for (int ct = 0; ct < 4; ++ct) {
                const float p0 = __builtin_amdgcn_exp2f(s[st][ct][0]);
                const float p1 = __builtin_amdgcn_exp2f(s[st][ct][1]);
                const float p2 = __builtin_amdgcn_exp2f(s[st][ct][2]);
                const float p3 = __builtin_amdgcn_exp2f(s[st][ct][3]);
                sacc[st] += (p0 + p1) + (p2 + p3);
                const hv2 lo = __builtin_amdgcn_cvt_pkrtz(p0, p1);
                const hv2 hi = __builtin_amdgcn_cvt_pkrtz(p2, p3);
                pk[st][ct] = __builtin_shufflevector(lo, hi, 0, 1, 2, 3);
            }

        #pragma unroll
        for (int jc = 0; jc < 4; ++jc) {
            const int csv = ((jc << 1) | (lq >> 1)) ^ (lr & 7);
            #pragma unroll
            for (int ctd = 0; ctd < 4; ++ctd) {
                const hv4 av = *(const hv4*)&Vs[(ctd * 16 + lr) * 64 + csv * 8 + (lq & 1) * 4];
                #pragma unroll
                for (int st = 0; st < 2; ++st)
                    ot[st][ctd] = __builtin_amdgcn_mfma_f32_16x16x16f16(av, pk[st][jc], ot[st][ctd], 0, 0, 0);
            }
        }
    }

    #pragma unroll
    for (int st = 0; st < 2; ++st) {
        float l = sacc[st];
        l += __shfl_xor(l, 16, 64);
        l += __shfl_xor(l, 32, 64);
        const float linv = 1.f / l;
        const int i = q0 + st * 64 + wv * 16 + lr;
        if (i < 577) {
            #pragma unroll
            for (int ctd = 0; ctd < 4; ++ctd) {
                h4f ov;
                #pragma unroll
                for (int r = 0; r < 4; ++r) ov[r] = (_Float16)(ot[st][ctd][r] * linv);
                *(h4f*)(Og + ((size_t)(b * 577 + i)) * 768 + h * 64 + ctd * 16 + lq * 4) = ov;
            }
        }
    }
}

// ---------------- GEMM2: out = O @ W_out + b_out (fp32 out), pipelined ------
__global__ __launch_bounds__(512, 4) void gemm_out(const _Float16* __restrict__ Og,
                                                   const _Float16* __restrict__ wT,
                                                   const float* __restrict__ bias,
                                                   float* __restrict__ out) {
    __shared__ _Float16 As[2][128 * 32];
    __shared__ _Float16 Bs[2][256 * 32];
    const int m0 = blockIdx.x * 128, n0 = blockIdx.y * 256;
    const int tid = threadIdx.x;
    const int lane = tid & 63, wv = tid >> 6;
    const int wrow = wv >> 2, wcol = wv & 3;
    const int lr = lane & 15, lq = lane >> 4;

    const int ra  = tid >> 2,         ca  = (tid & 3) * 8;
    const int rb0 = tid >> 2,         cb0 = (tid & 3) * 8;
    const int rb1 = (512 + tid) >> 2, cb1 = (tid & 3) * 8;

    floatx4 acc[4][4];
    const floatx4 fz = {0.f, 0.f, 0.f, 0.f};
    for (int i = 0; i < 4; ++i)
        for (int j = 0; j < 4; ++j) acc[i][j] = fz;

    #define STAGE_OUT(ki, bf)                                                     \
        do {                                                                      \
            const int kk_ = (ki) * 32;                                            \
            gl_lds16(Og + (size_t)(m0 + ra) * 768 + kk_ + ca, &As[bf][wv*64*8]);  \
            gl_lds16(wT + (size_t)(n0 + rb0) * 768 + kk_ + cb0, &Bs[bf][wv*64*8]);\
            gl_lds16(wT + (size_t)(n0 + rb1) * 768 + kk_ + cb1,                   \
                     &Bs[bf][(512 + wv*64) * 8]);                                 \
        } while (0)

    STAGE_OUT(0, 0);
    for (int ki = 0; ki < 24; ++ki) {
        const int bf = ki & 1;
        if (ki < 23) {
            STAGE_OUT(ki + 1, bf ^ 1);
            asm volatile("s_waitcnt vmcnt(3)" ::: "memory");
        } else {
            asm volatile("s_waitcnt vmcnt(0)" ::: "memory");
        }
        asm volatile("s_barrier" ::: "memory");

        half8 af[4], bfr[4];
        #pragma unroll
        for (int i = 0; i < 4; ++i)
            af[i] = *(const half8*)&As[bf][(wrow * 64 + i * 16 + lr) * 32 + lq * 8];
        #pragma unroll
        for (int j = 0; j < 4; ++j)
            bfr[j] = *(const half8*)&Bs[bf][(wcol * 64 + j * 16 + lr) * 32 + lq * 8];
        #pragma unroll
        for (int i = 0; i < 4; ++i)
            #pragma unroll
            for (int j = 0; j < 4; ++j)
                acc[i][j] = __builtin_amdgcn_mfma_f32_16x16x32_f16(af[i], bfr[j], acc[i][j], 0, 0, 0);

        asm volatile("s_waitcnt lgkmcnt(0)\n\ts_barrier" ::: "memory");
    }
    #undef STAGE_OUT

    #pragma unroll
    for (int j = 0; j < 4; ++j) {
        const int c = n0 + wcol * 64 + j * 16 + lr;
        const float bv = bias[c];
        #pragma unroll
        for (int i = 0; i < 4; ++i)
            #pragma unroll
            for (int r = 0; r < 4; ++r) {
                const int row = m0 + wrow * 64 + i * 16 + lq * 4 + r;
                if (row < MTOT) out[(size_t)row * 768 + c] = acc[i][j][r] + bv;
            }
    }
}

// ---------------------------------------------------------------------------
extern "C" void kernel_launch(void* const* d_in, const int* in_sizes, int n_in,
                              void* d_out, int out_size, void* d_ws, size_t ws_size,
                              hipStream_t stream) {
    const float* x      = (const float*)d_in[0];   // [32,577,768]
    const float* W_qkv  = (const float*)d_in[1];   // [768,2304]
    const float* scale  = (const float*)d_in[2];   // [12]
    const float* W_out  = (const float*)d_in[3];   // [768,768]
    const float* b_out  = (const float*)d_in[4];   // [768]
    float* out = (float*)d_out;

    // workspace (f16), Og aliases x16 (x16 dead after gemm_qkv):
    //   x16/Og [18560,768]  28,508,160 B
    //   q  [32,12,577,64]   28,360,704 B
    //   k  [32,12,577,64]   28,360,704 B
    //   vT [32,12,64,584]   28,704,768 B
    //   WqkvT [2304,768]     3,538,944 B
    //   WoutT [768,768]      1,179,648 B    total ~118.7 MB
    char* ws = (char*)d_ws;
    _Float16* x16   = (_Float16*)(ws);
    _Float16* Og    = x16;
    _Float16* qg    = (_Float16*)(ws + 28508160u);
    _Float16* kg    = (_Float16*)(ws + 28508160u + 28360704u);
    _Float16* vT    = (_Float16*)(ws + 28508160u + 2u * 28360704u);
    _Float16* WqkvT = (_Float16*)(ws + 28508160u + 2u * 28360704u + 28704768u);
    _Float16* WoutT = WqkvT + (size_t)2304 * 768;

    cvt_x<<<6960, 256, 0, stream>>>(x, x16);
    transpose_w<<<dim3(72, 24), 256, 0, stream>>>(W_qkv, WqkvT, 768, 2304);
    transpose_w<<<dim3(24, 24), 256, 0, stream>>>(W_out, WoutT, 768, 768);
    gemm_qkv<<<dim3(145, 9), 512, 0, stream>>>(x16, WqkvT, scale, qg, kg, vT);
    attn_kernel<<<dim3(5, 12, 32), 256, 0, stream>>>(qg, kg, vT, Og);
    gemm_out<<<dim3(145, 3), 512, 0, stream>>>(Og, WoutT, b_out, out);
}